// Round 3
// baseline (8080.669 us; speedup 1.0000x reference)
//
#include <hip/hip_runtime.h>

// ---------------------------------------------------------------------------
// 2-layer LSTM, T=1024, B=32, D=256, H=512. Inputs fp32, OUTPUT fp32.
//   pack_w3: fp32 {W_hh0, W_hh1, W_ih1} -> bf16 MFMA B-fragment order.
//   gemm_xp: xp0 = x @ W_ih0^T (bf16 MFMA).
//   lstm_pipe2 (R9 = R8 with static-LDS fix: ONE shared staging buffer,
//   41.7 KB total — R8's 74.7 KB broke the 64 KB static limit = build fail):
//     role0 L0: layer0 recurrence. Fully fire-and-forget epilogue:
//       h0 pairs {data,phase} -> hbuf0 (self recurrence), hs0 pairs -> depth-8
//       ring (feeds L1). NO vmcnt acks, NO flags. Backpressure on the ring via
//       a lazily-polled L1 progress word (free in steady state).
//     role1 L1: FUSED xp1+recurrence: gates = hs0(t)@Wih1^T + h1(t)@Whh1^T + b1
//       (two 32-MFMA passes into one fp32 acc, sharing one LDS buffer).
//       h1(t) pair loads are issued BEFORE the ring poll + xp MFMAs so their
//       latency hides under compute; validated after the xp pass.
//   All exchange via proven relaxed agent atomics (R5-R7), all self-validating.
// ---------------------------------------------------------------------------

typedef __bf16 bf16x8 __attribute__((ext_vector_type(8)));
typedef float  f32x4  __attribute__((ext_vector_type(4)));
typedef float  f32x2  __attribute__((ext_vector_type(2)));
typedef unsigned long long u64;
typedef unsigned int u32;

#define MFMA16(a, b, c) __builtin_amdgcn_mfma_f32_16x16x32_bf16((a), (b), (c), 0, 0, 0)
#define SCOPE_AGENT __HIP_MEMORY_SCOPE_AGENT
#define AL64(p) __hip_atomic_load((p), __ATOMIC_RELAXED, SCOPE_AGENT)

__device__ __forceinline__ float fsigm(float x) { return 1.0f / (1.0f + __expf(-x)); }
__device__ __forceinline__ float ftanh(float x) {
    x = fminf(15.0f, fmaxf(-15.0f, x));
    float e = __expf(2.0f * x);
    return (e - 1.0f) / (e + 1.0f);
}

__device__ __forceinline__ bf16x8 frag_from(u64 lo, u64 hi) {
    union { u64 u[2]; bf16x8 v; } x;
    x.u[0] = lo; x.u[1] = hi;
    return x.v;
}

// Blocking combined poll+load of one 32x512 bf16 snapshot stored as
// {bf16x2 data (lo), u32 phase (hi)} pairs. Chunk f=(i*256+tid) covers pairs
// {2f,2f+1}; on success hv[i] holds 4 bf16 = elements 4f..4f+3.
// Slot-overwrite safety: a producer can only rewrite a slot after completing
// its NEXT step's poll, which needs THIS consumer's pairs -> data-dependency
// chain prevents phase overshoot (verified logic R7, harness-passed).
__device__ __forceinline__ void poll_pairs16(const u64* __restrict__ base, int tid,
                                             u32 ph, u64* hv) {
    u64 q0[16], q1[16];
    u32 bad;
    do {
#pragma unroll
        for (int i = 0; i < 16; i++) {
            int f = i * 256 + tid;
            q0[i] = AL64(base + 2 * f);
            q1[i] = AL64(base + 2 * f + 1);
        }
        bad = 0;
#pragma unroll
        for (int i = 0; i < 16; i++)
            bad |= ((u32)(q0[i] >> 32) ^ ph) | ((u32)(q1[i] >> 32) ^ ph);
    } while (bad != 0);
#pragma unroll
    for (int i = 0; i < 16; i++) hv[i] = (q0[i] & 0xFFFFFFFFull) | (q1[i] << 32);
}

// ---------------------------------------------------------------------------
// Pack [2048][512] fp32 -> per-(wg,wave,ktile) bf16 B-fragment order.
// ---------------------------------------------------------------------------
__global__ void pack_w3(const float* __restrict__ W0, const float* __restrict__ W1,
                        const float* __restrict__ W2, __bf16* __restrict__ O0,
                        __bf16* __restrict__ O1, __bf16* __restrict__ O2) {
    int gtid = blockIdx.x * 256 + threadIdx.x;          // 0 .. 393215
    int sel  = gtid >> 17;                              // 0,1,2
    const float* W = (sel == 0) ? W0 : (sel == 1) ? W1 : W2;
    __bf16* WB     = (sel == 0) ? O0 : (sel == 1) ? O1 : O2;
    int tid  = gtid & 131071;
    int lane = tid & 63;
    int kk   = (tid >> 6) & 15;
    int v    = (tid >> 10) & 3;
    int w    = tid >> 12;                               // 0..31
    int n    = v * 16 + (lane & 15);
    int grow = (n >> 4) * 512 + w * 16 + (n & 15);
    int k0   = kk * 32 + (lane >> 4) * 8;
    const float* src = W + (size_t)grow * 512 + k0;
    bf16x8 val;
#pragma unroll
    for (int e = 0; e < 8; e++) val[e] = (__bf16)src[e];
    *(bf16x8*)(WB + (size_t)tid * 8) = val;
}

// ---------------------------------------------------------------------------
// xp0[r][n] = sum_k x_perm(r)[k] * W[n][k], r = t*32+b, x is [B,T,D] fp32.
// ---------------------------------------------------------------------------
__global__ __launch_bounds__(256, 2) void gemm_xp(const float* __restrict__ A,
                                                  const float* __restrict__ W,
                                                  __bf16* __restrict__ out, int K) {
    const int tid = threadIdx.x, lane = tid & 63, wv = tid >> 6;
    const int bm = blockIdx.x >> 4, bn = blockIdx.x & 15;
    const int m_base = bm * 128 + (wv & 1) * 64;
    const int n_base = bn * 128 + (wv >> 1) * 64;
    const int kq = (lane >> 4) * 8;
    const int rl = lane & 15;

    f32x4 acc[4][4];
#pragma unroll
    for (int i = 0; i < 4; i++)
#pragma unroll
        for (int j = 0; j < 4; j++) acc[i][j] = (f32x4){0.f, 0.f, 0.f, 0.f};

    const int nk = K >> 5;
    for (int kk = 0; kk < nk; kk++) {
        int k0 = kk * 32 + kq;
        bf16x8 af[4], bfr[4];
#pragma unroll
        for (int mt = 0; mt < 4; mt++) {
            int row = m_base + mt * 16 + rl;
            const float* ap = A + (size_t)((row & 31) * 1024 + (row >> 5)) * K + k0;
#pragma unroll
            for (int e = 0; e < 8; e++) af[mt][e] = (__bf16)ap[e];
        }
#pragma unroll
        for (int nt = 0; nt < 4; nt++) {
            int n = n_base + nt * 16 + rl;
            const float* wp = W + (size_t)n * K + k0;
#pragma unroll
            for (int e = 0; e < 8; e++) bfr[nt][e] = (__bf16)wp[e];
        }
#pragma unroll
        for (int mt = 0; mt < 4; mt++)
#pragma unroll
            for (int nt = 0; nt < 4; nt++)
                acc[mt][nt] = MFMA16(af[mt], bfr[nt], acc[mt][nt]);
    }

    const int rq = (lane >> 4) * 4;
#pragma unroll
    for (int mt = 0; mt < 4; mt++)
#pragma unroll
        for (int nt = 0; nt < 4; nt++)
#pragma unroll
            for (int r = 0; r < 4; r++) {
                int row = m_base + mt * 16 + rq + r;
                int col = n_base + nt * 16 + rl;
                out[(size_t)row * 2048 + col] = (__bf16)acc[mt][nt][r];
            }
}

// ---------------------------------------------------------------------------
// 2-stage pipelined recurrence. 64 wgs x 256. role = blockIdx/32, w = %32.
// wg w (either role) owns h-cols [w*16, w*16+16) x 4 gates.
// Static LDS: 33.0 KB staging + 8.7 KB gates = 41.7 KB (< 64 KB limit).
// ---------------------------------------------------------------------------
__global__ __launch_bounds__(256, 1) void lstm_pipe2(
    const __bf16* __restrict__ xp0,    // [32768][2048] bf16, row = t*32+b
    const __bf16* __restrict__ WB0,    // W_hh0 packed
    const __bf16* __restrict__ WBw1,   // W_hh1 packed
    const __bf16* __restrict__ WBi1,   // W_ih1 packed
    const float* __restrict__ bias0,
    const float* __restrict__ bias1,
    u64* __restrict__ hbuf0,           // [2][8192] {data,phase} pairs, zeroed
    u64* __restrict__ hbuf1,           // [2][8192] pairs, zeroed
    u64* __restrict__ ring,            // [8][8192] hs0 pairs, zeroed
    u32* __restrict__ prog1,           // [32] L1 progress, zeroed
    float* __restrict__ out_f32,       // [32][1024][512]
    float* __restrict__ hn_out,        // [2][32][512]
    float* __restrict__ cn_out) {      // [2][32][512]
    const int tid  = threadIdx.x;
    const int role = blockIdx.x >> 5;   // 0=L0, 1=fused L1
    const int w    = blockIdx.x & 31;
    const int lane = tid & 63;
    const int wv   = tid >> 6;

    __shared__ __bf16 lds_h[32 * 516];  // staged snapshot (stride 516), reused
    __shared__ float  g_lds[32 * 68];   // gates [32 b][64 cols +4]

    // --- elementwise mapping: thread -> (b, j0, j0+1) ---
    const int b  = tid >> 3;
    const int jp = tid & 7;
    const int j0 = w * 16 + jp * 2;
    const int pi = b * 256 + w * 8 + jp;   // pair index in snapshots
    const int arow = lane & 15;
    const int kq8  = (lane >> 4) * 8;

    f32x2 bsv[4];
    {
        const float* bias = (role == 0) ? bias0 : bias1;
#pragma unroll
        for (int g = 0; g < 4; g++) bsv[g] = *(const f32x2*)(bias + g * 512 + j0);
    }
    float cc0 = 0.f, cc1 = 0.f;

    if (role == 0) {
        // =================== L0: layer-0 recurrence ===================
        bf16x8 wreg[16];
        {
            const __bf16* wb = WB0 + (size_t)(w * 4 + wv) * 16 * 512 + lane * 8;
#pragma unroll
            for (int kk = 0; kk < 16; kk++) wreg[kk] = *(const bf16x8*)(wb + kk * 512);
        }
        u32 xc[4], xn[4];
#pragma unroll
        for (int g = 0; g < 4; g++)
            xc[g] = *(const u32*)(xp0 + (size_t)b * 2048 + g * 512 + j0);

        for (int t = 0; t < 1024; t++) {
            // backpressure pre-load (joins the poll's drain, ~free)
            u32 pv = 0;
            if (tid < 32 && t >= 8)
                pv = __hip_atomic_load(&prog1[tid], __ATOMIC_RELAXED, SCOPE_AGENT);

            // h0(t) self-validating poll
            u64 hv[16];
            if (t > 0) {
                poll_pairs16(hbuf0 + (size_t)(t & 1) * 8192, tid, (u32)(t >> 1) + 1, hv);
            } else {
#pragma unroll
                for (int i = 0; i < 16; i++) hv[i] = 0;
            }
            // backpressure finalize: ring slot t&7 overwrite needs L1 past t-8
            if (tid < 32 && t >= 8)
                while ((int)pv < t - 7)
                    pv = __hip_atomic_load(&prog1[tid], __ATOMIC_RELAXED, SCOPE_AGENT);

            // xp0 prefetch for t+1 (lands during MFMA, consumed next step)
            {
                int tn = (t < 1023) ? t + 1 : 1023;
#pragma unroll
                for (int g = 0; g < 4; g++)
                    xn[g] = *(const u32*)(xp0 + (size_t)(tn * 32 + b) * 2048 + g * 512 + j0);
            }

            // stage h0 -> lds_h
#pragma unroll
            for (int i = 0; i < 16; i++) {
                int f  = (i * 256 + tid) * 4;
                int br = f >> 9, col = f & 511;
                *(u64*)(lds_h + br * 516 + col) = hv[i];
            }
            __syncthreads();

            // 32 MFMAs: h0(t) @ W_hh0^T
            f32x4 acc0 = (f32x4){0.f, 0.f, 0.f, 0.f};
            f32x4 acc1 = (f32x4){0.f, 0.f, 0.f, 0.f};
#pragma unroll
            for (int kk = 0; kk < 16; kk++) {
                const __bf16* p0 = lds_h + arow * 516 + kq8 + kk * 32;
                const __bf16* p1 = p0 + 16 * 516;
                bf16x8 a0 = frag_from(*(const u64*)p0, *(const u64*)(p0 + 4));
                bf16x8 a1 = frag_from(*(const u64*)p1, *(const u64*)(p1 + 4));
                acc0 = MFMA16(a0, wreg[kk], acc0);
                acc1 = MFMA16(a1, wreg[kk], acc1);
            }
            {
                int col   = wv * 16 + (lane & 15);
                int rbase = (lane >> 4) * 4;
#pragma unroll
                for (int r = 0; r < 4; r++) {
                    g_lds[(rbase + r) * 68 + col]      = acc0[r];
                    g_lds[(16 + rbase + r) * 68 + col] = acc1[r];
                }
            }
            __syncthreads();

            // gates + state update
            float hf0, hf1;
            {
                union { u32 u; __bf16 v2[2]; } xi, xf, xg, xo;
                xi.u = xc[0]; xf.u = xc[1]; xg.u = xc[2]; xo.u = xc[3];
                const float* gl = g_lds + b * 68 + jp * 2;
                f32x2 gi = *(const f32x2*)(gl);
                f32x2 gf = *(const f32x2*)(gl + 16);
                f32x2 gg = *(const f32x2*)(gl + 32);
                f32x2 go = *(const f32x2*)(gl + 48);

                float i0 = fsigm(gi[0] + (float)xi.v2[0] + bsv[0][0]);
                float f0 = fsigm(gf[0] + (float)xf.v2[0] + bsv[1][0]);
                float g0 = ftanh(gg[0] + (float)xg.v2[0] + bsv[2][0]);
                float o0 = fsigm(go[0] + (float)xo.v2[0] + bsv[3][0]);
                cc0 = f0 * cc0 + i0 * g0;
                hf0 = o0 * ftanh(cc0);

                float i1 = fsigm(gi[1] + (float)xi.v2[1] + bsv[0][1]);
                float f1 = fsigm(gf[1] + (float)xf.v2[1] + bsv[1][1]);
                float g1 = ftanh(gg[1] + (float)xg.v2[1] + bsv[2][1]);
                float o1 = fsigm(go[1] + (float)xo.v2[1] + bsv[3][1]);
                cc1 = f1 * cc1 + i1 * g1;
                hf1 = o1 * ftanh(cc1);
            }
            union { __bf16 v2[2]; u32 u; } hu;
            hu.v2[0] = (__bf16)hf0; hu.v2[1] = (__bf16)hf1;

            // fire-and-forget: self recurrence pair + hs0 ring pair. No acks.
            u64 hp_rec = (u64)hu.u | ((u64)((u32)((t + 1) >> 1) + 1) << 32);
            __hip_atomic_store(hbuf0 + (size_t)((t + 1) & 1) * 8192 + pi, hp_rec,
                               __ATOMIC_RELAXED, SCOPE_AGENT);
            u64 hp_ring = (u64)hu.u | ((u64)(u32)(t + 1) << 32);
            __hip_atomic_store(ring + (size_t)(t & 7) * 8192 + pi, hp_ring,
                               __ATOMIC_RELAXED, SCOPE_AGENT);

            if (t == 1023) {
                *(f32x2*)(hn_out + (size_t)b * 512 + j0) = (f32x2){hf0, hf1};
                *(f32x2*)(cn_out + (size_t)b * 512 + j0) = (f32x2){cc0, cc1};
            }
#pragma unroll
            for (int g = 0; g < 4; g++) xc[g] = xn[g];
        }
    } else {
        // =============== L1: fused xp1 + layer-1 recurrence ===============
        bf16x8 wregA[16], wregB[16];   // A: W_ih1 (hs0 pass), B: W_hh1 (h1 pass)
        {
            const __bf16* wa = WBi1 + (size_t)(w * 4 + wv) * 16 * 512 + lane * 8;
            const __bf16* wb = WBw1 + (size_t)(w * 4 + wv) * 16 * 512 + lane * 8;
#pragma unroll
            for (int kk = 0; kk < 16; kk++) {
                wregA[kk] = *(const bf16x8*)(wa + kk * 512);
                wregB[kk] = *(const bf16x8*)(wb + kk * 512);
            }
        }

        for (int t = 0; t < 1024; t++) {
            // (a) first-attempt h1(t) pair loads — validated after the xp pass
            u64 qa[16], qb[16];
            if (t > 0) {
                const u64* hb = hbuf1 + (size_t)(t & 1) * 8192;
#pragma unroll
                for (int i = 0; i < 16; i++) {
                    int f = i * 256 + tid;
                    qa[i] = AL64(hb + 2 * f);
                    qb[i] = AL64(hb + 2 * f + 1);
                }
            }

            // (b) hs0(t) ring poll (first-try hit once L0 runs ahead)
            u64 hvx[16];
            poll_pairs16(ring + (size_t)(t & 7) * 8192, tid, (u32)(t + 1), hvx);

            // (c) stage hs0 -> lds_h
#pragma unroll
            for (int i = 0; i < 16; i++) {
                int f  = (i * 256 + tid) * 4;
                int br = f >> 9, col = f & 511;
                *(u64*)(lds_h + br * 516 + col) = hvx[i];
            }
            __syncthreads();

            // (d) xp pass: hs0(t) @ W_ih1^T  (h1 loads still in flight)
            f32x4 acc0 = (f32x4){0.f, 0.f, 0.f, 0.f};
            f32x4 acc1 = (f32x4){0.f, 0.f, 0.f, 0.f};
#pragma unroll
            for (int kk = 0; kk < 16; kk++) {
                const __bf16* p0 = lds_h + arow * 516 + kq8 + kk * 32;
                const __bf16* p1 = p0 + 16 * 516;
                bf16x8 a0 = frag_from(*(const u64*)p0, *(const u64*)(p0 + 4));
                bf16x8 a1 = frag_from(*(const u64*)p1, *(const u64*)(p1 + 4));
                acc0 = MFMA16(a0, wregA[kk], acc0);
                acc1 = MFMA16(a1, wregA[kk], acc1);
            }
            __syncthreads();   // all waves done reading hs0 before overwrite

            // (e) validate h1(t); retry only if stores not yet visible
            u64 hv[16];
            if (t > 0) {
                const u64* hb = hbuf1 + (size_t)(t & 1) * 8192;
                u32 ph = (u32)(t >> 1) + 1;
                u32 bad = 0;
#pragma unroll
                for (int i = 0; i < 16; i++)
                    bad |= ((u32)(qa[i] >> 32) ^ ph) | ((u32)(qb[i] >> 32) ^ ph);
                while (bad != 0) {
#pragma unroll
                    for (int i = 0; i < 16; i++) {
                        int f = i * 256 + tid;
                        qa[i] = AL64(hb + 2 * f);
                        qb[i] = AL64(hb + 2 * f + 1);
                    }
                    bad = 0;
#pragma unroll
                    for (int i = 0; i < 16; i++)
                        bad |= ((u32)(qa[i] >> 32) ^ ph) | ((u32)(qb[i] >> 32) ^ ph);
                }
#pragma unroll
                for (int i = 0; i < 16; i++)
                    hv[i] = (qa[i] & 0xFFFFFFFFull) | (qb[i] << 32);
            } else {
#pragma unroll
                for (int i = 0; i < 16; i++) hv[i] = 0;
            }

            // (f) stage h1 -> lds_h (reuse)
#pragma unroll
            for (int i = 0; i < 16; i++) {
                int f  = (i * 256 + tid) * 4;
                int br = f >> 9, col = f & 511;
                *(u64*)(lds_h + br * 516 + col) = hv[i];
            }
            __syncthreads();

            // (g) recurrent pass: + h1(t) @ W_hh1^T (same accumulators)
#pragma unroll
            for (int kk = 0; kk < 16; kk++) {
                const __bf16* p0 = lds_h + arow * 516 + kq8 + kk * 32;
                const __bf16* p1 = p0 + 16 * 516;
                bf16x8 a0 = frag_from(*(const u64*)p0, *(const u64*)(p0 + 4));
                bf16x8 a1 = frag_from(*(const u64*)p1, *(const u64*)(p1 + 4));
                acc0 = MFMA16(a0, wregB[kk], acc0);
                acc1 = MFMA16(a1, wregB[kk], acc1);
            }
            {
                int col   = wv * 16 + (lane & 15);
                int rbase = (lane >> 4) * 4;
#pragma unroll
                for (int r = 0; r < 4; r++) {
                    g_lds[(rbase + r) * 68 + col]      = acc0[r];
                    g_lds[(16 + rbase + r) * 68 + col] = acc1[r];
                }
            }
            __syncthreads();

            // (h) gates + state update (bias only; xp is inside acc)
            float hf0, hf1;
            {
                const float* gl = g_lds + b * 68 + jp * 2;
                f32x2 gi = *(const f32x2*)(gl);
                f32x2 gf = *(const f32x2*)(gl + 16);
                f32x2 gg = *(const f32x2*)(gl + 32);
                f32x2 go = *(const f32x2*)(gl + 48);

                float i0 = fsigm(gi[0] + bsv[0][0]);
                float f0 = fsigm(gf[0] + bsv[1][0]);
                float g0 = ftanh(gg[0] + bsv[2][0]);
                float o0 = fsigm(go[0] + bsv[3][0]);
                cc0 = f0 * cc0 + i0 * g0;
                hf0 = o0 * ftanh(cc0);

                float i1 = fsigm(gi[1] + bsv[0][1]);
                float f1 = fsigm(gf[1] + bsv[1][1]);
                float g1 = ftanh(gg[1] + bsv[2][1]);
                float o1 = fsigm(go[1] + bsv[3][1]);
                cc1 = f1 * cc1 + i1 * g1;
                hf1 = o1 * ftanh(cc1);
            }
            union { __bf16 v2[2]; u32 u; } hu;
            hu.v2[0] = (__bf16)hf0; hu.v2[1] = (__bf16)hf1;

            // fire-and-forget: self recurrence pair, output, progress
            u64 hp_rec = (u64)hu.u | ((u64)((u32)((t + 1) >> 1) + 1) << 32);
            __hip_atomic_store(hbuf1 + (size_t)((t + 1) & 1) * 8192 + pi, hp_rec,
                               __ATOMIC_RELAXED, SCOPE_AGENT);
            *(f32x2*)(out_f32 + (size_t)b * 524288 + (size_t)t * 512 + j0) =
                (f32x2){hf0, hf1};
            if (tid == 0)
                __hip_atomic_store(&prog1[w], (u32)(t + 1), __ATOMIC_RELAXED, SCOPE_AGENT);

            if (t == 1023) {
                *(f32x2*)(hn_out + 16384 + (size_t)b * 512 + j0) = (f32x2){hf0, hf1};
                *(f32x2*)(cn_out + 16384 + (size_t)b * 512 + j0) = (f32x2){cc0, cc1};
            }
        }
    }
}

// ---------------------------------------------------------------------------
extern "C" void kernel_launch(void* const* d_in, const int* in_sizes, int n_in,
                              void* d_out, int out_size, void* d_ws, size_t ws_size,
                              hipStream_t stream) {
    (void)in_sizes; (void)n_in; (void)out_size; (void)ws_size;
    const float* x    = (const float*)d_in[0];  // [32][1024][256] fp32
    const float* Wih0 = (const float*)d_in[1];  // [2048][256] fp32
    const float* b0   = (const float*)d_in[2];  // [2048] fp32
    const float* Whh0 = (const float*)d_in[3];  // [2048][512] fp32
    const float* Wih1 = (const float*)d_in[4];  // [2048][512] fp32
    const float* b1   = (const float*)d_in[5];  // [2048] fp32
    const float* Whh1 = (const float*)d_in[6];  // [2048][512] fp32
    float* dout = (float*)d_out;  // fp32: out(16777216) | h_n(2*16384) | c_n(2*16384)

    char* wsb = (char*)d_ws;
    u32*    prog1 = (u32*)wsb;                                  // 4 KB reserve
    u64*    hbuf0 = (u64*)(wsb + (4 << 10));                    // 128 KB
    u64*    hbuf1 = (u64*)(wsb + (4 << 10) + (128 << 10));      // 128 KB
    u64*    ring  = (u64*)(wsb + (4 << 10) + (256 << 10));      // 512 KB
    __bf16* WB0   = (__bf16*)(wsb + (1 << 20));                 // 2 MB
    __bf16* WBw1  = (__bf16*)(wsb + (3 << 20));                 // 2 MB
    __bf16* WBi1  = (__bf16*)(wsb + (5 << 20));                 // 2 MB
    __bf16* xpb   = (__bf16*)(wsb + (8 << 20));                 // 128 MB

    // zero prog + both pair double-buffers + ring (contiguous 772 KB)
    (void)hipMemsetAsync(wsb, 0, 772 << 10, stream);

    pack_w3<<<dim3(1536), dim3(256), 0, stream>>>(Whh0, Whh1, Wih1, WB0, WBw1, WBi1);

    // xp0 = x @ Wih0^T  (K=256, fp32 A, permuted rows)
    gemm_xp<<<dim3(4096), dim3(256), 0, stream>>>(x, Wih0, xpb, 256);

    lstm_pipe2<<<dim3(64), dim3(256), 0, stream>>>(
        xpb, WB0, WBw1, WBi1, b0, b1, hbuf0, hbuf1, ring, prog1,
        dout, dout + 16777216, dout + 16777216 + 32768);
}

// Round 4
// 4747.166 us; speedup vs baseline: 1.7022x; 1.7022x over previous
//
#include <hip/hip_runtime.h>

// ---------------------------------------------------------------------------
// 2-layer LSTM, T=1024, B=32, D=256, H=512. Inputs fp32, OUTPUT fp32.
//   pack_w3: fp32 {W_hh0, W_hh1, W_ih1} -> bf16 MFMA B-fragment order.
//   gemm_xp: xp0 = x @ W_ih0^T (bf16 MFMA).
//   lstm_pipe3 (R10): 96 wgs, 3 roles of 32 — baseline 3-stage shape with the
//   ordered obligations surgically removed:
//     role0 L0 : pair-poll h0 (selective retry), MFMA, gates; fire-and-forget
//                stores of h0 pairs + hs0 pairs into a depth-16 ring. No acks,
//                no flags. Ring backpressure via fX[.][t-16] (write-once,
//                pre-loaded before the poll -> off critical path).
//     role1 XP1: pair-polls the hs0 ring (fan-in 32), computes xp1, stores
//                ring slot + vmcnt + fX flag (proven baseline edge; has slack).
//     role2 L1 : baseline loop: fX fan-in-1 (prefetched 1 step early) + direct
//                xp loads + self-recurrence pair-poll (selective retry);
//                fire-and-forget h1 pairs + fL1 flag (no vmcnt).
//   Per recurrence step: ONE serial MALL round trip + compute.
// ---------------------------------------------------------------------------

typedef __bf16 bf16x8 __attribute__((ext_vector_type(8)));
typedef float  f32x4  __attribute__((ext_vector_type(4)));
typedef float  f32x2  __attribute__((ext_vector_type(2)));
typedef unsigned long long u64;
typedef unsigned int u32;

#define MFMA16(a, b, c) __builtin_amdgcn_mfma_f32_16x16x32_bf16((a), (b), (c), 0, 0, 0)
#define SCOPE_AGENT __HIP_MEMORY_SCOPE_AGENT
#define AL64(p) __hip_atomic_load((p), __ATOMIC_RELAXED, SCOPE_AGENT)
#define AL32(p) __hip_atomic_load((p), __ATOMIC_RELAXED, SCOPE_AGENT)
#define AS64(p, v) __hip_atomic_store((p), (v), __ATOMIC_RELAXED, SCOPE_AGENT)
#define AS32(p, v) __hip_atomic_store((p), (v), __ATOMIC_RELAXED, SCOPE_AGENT)

__device__ __forceinline__ float fsigm(float x) { return 1.0f / (1.0f + __expf(-x)); }
__device__ __forceinline__ float ftanh(float x) {
    x = fminf(15.0f, fmaxf(-15.0f, x));
    float e = __expf(2.0f * x);
    return (e - 1.0f) / (e + 1.0f);
}

__device__ __forceinline__ bf16x8 frag_from(u64 lo, u64 hi) {
    union { u64 u[2]; bf16x8 v; } x;
    x.u[0] = lo; x.u[1] = hi;
    return x.v;
}

// Selective-retry poll of one 32x512 bf16 snapshot stored as {bf16x2, phase}
// pairs. First sweep loads everything once; retries reload ONLY stale chunks
// (exec-masked), so steady-state traffic ~= one sweep. On success hv[i] is
// the u64-of-4-bf16 layout the LDS stage expects.
__device__ __forceinline__ void poll_sel16(const u64* __restrict__ base, int tid,
                                           u32 ph, u64* hv) {
    u64 q0[16], q1[16];
#pragma unroll
    for (int i = 0; i < 16; i++) {
        int f = i * 256 + tid;
        q0[i] = AL64(base + 2 * f);
        q1[i] = AL64(base + 2 * f + 1);
    }
    for (;;) {
        u32 bad = 0;
#pragma unroll
        for (int i = 0; i < 16; i++)
            bad |= ((u32)(q0[i] >> 32) ^ ph) | ((u32)(q1[i] >> 32) ^ ph);
        if (bad == 0) break;
#pragma unroll
        for (int i = 0; i < 16; i++) {
            int f = i * 256 + tid;
            if ((u32)(q0[i] >> 32) != ph) q0[i] = AL64(base + 2 * f);
            if ((u32)(q1[i] >> 32) != ph) q1[i] = AL64(base + 2 * f + 1);
        }
    }
#pragma unroll
    for (int i = 0; i < 16; i++) hv[i] = (q0[i] & 0xFFFFFFFFull) | (q1[i] << 32);
}

// ---------------------------------------------------------------------------
// Pack [2048][512] fp32 -> per-(wg,wave,ktile) bf16 B-fragment order.
// ---------------------------------------------------------------------------
__global__ void pack_w3(const float* __restrict__ W0, const float* __restrict__ W1,
                        const float* __restrict__ W2, __bf16* __restrict__ O0,
                        __bf16* __restrict__ O1, __bf16* __restrict__ O2) {
    int gtid = blockIdx.x * 256 + threadIdx.x;          // 0 .. 393215
    int sel  = gtid >> 17;                              // 0,1,2
    const float* W = (sel == 0) ? W0 : (sel == 1) ? W1 : W2;
    __bf16* WB     = (sel == 0) ? O0 : (sel == 1) ? O1 : O2;
    int tid  = gtid & 131071;
    int lane = tid & 63;
    int kk   = (tid >> 6) & 15;
    int v    = (tid >> 10) & 3;
    int w    = tid >> 12;                               // 0..31
    int n    = v * 16 + (lane & 15);
    int grow = (n >> 4) * 512 + w * 16 + (n & 15);
    int k0   = kk * 32 + (lane >> 4) * 8;
    const float* src = W + (size_t)grow * 512 + k0;
    bf16x8 val;
#pragma unroll
    for (int e = 0; e < 8; e++) val[e] = (__bf16)src[e];
    *(bf16x8*)(WB + (size_t)tid * 8) = val;
}

// ---------------------------------------------------------------------------
// xp0[r][n] = sum_k x_perm(r)[k] * W[n][k], r = t*32+b, x is [B,T,D] fp32.
// ---------------------------------------------------------------------------
__global__ __launch_bounds__(256, 2) void gemm_xp(const float* __restrict__ A,
                                                  const float* __restrict__ W,
                                                  __bf16* __restrict__ out, int K) {
    const int tid = threadIdx.x, lane = tid & 63, wv = tid >> 6;
    const int bm = blockIdx.x >> 4, bn = blockIdx.x & 15;
    const int m_base = bm * 128 + (wv & 1) * 64;
    const int n_base = bn * 128 + (wv >> 1) * 64;
    const int kq = (lane >> 4) * 8;
    const int rl = lane & 15;

    f32x4 acc[4][4];
#pragma unroll
    for (int i = 0; i < 4; i++)
#pragma unroll
        for (int j = 0; j < 4; j++) acc[i][j] = (f32x4){0.f, 0.f, 0.f, 0.f};

    const int nk = K >> 5;
    for (int kk = 0; kk < nk; kk++) {
        int k0 = kk * 32 + kq;
        bf16x8 af[4], bfr[4];
#pragma unroll
        for (int mt = 0; mt < 4; mt++) {
            int row = m_base + mt * 16 + rl;
            const float* ap = A + (size_t)((row & 31) * 1024 + (row >> 5)) * K + k0;
#pragma unroll
            for (int e = 0; e < 8; e++) af[mt][e] = (__bf16)ap[e];
        }
#pragma unroll
        for (int nt = 0; nt < 4; nt++) {
            int n = n_base + nt * 16 + rl;
            const float* wp = W + (size_t)n * K + k0;
#pragma unroll
            for (int e = 0; e < 8; e++) bfr[nt][e] = (__bf16)wp[e];
        }
#pragma unroll
        for (int mt = 0; mt < 4; mt++)
#pragma unroll
            for (int nt = 0; nt < 4; nt++)
                acc[mt][nt] = MFMA16(af[mt], bfr[nt], acc[mt][nt]);
    }

    const int rq = (lane >> 4) * 4;
#pragma unroll
    for (int mt = 0; mt < 4; mt++)
#pragma unroll
        for (int nt = 0; nt < 4; nt++)
#pragma unroll
            for (int r = 0; r < 4; r++) {
                int row = m_base + mt * 16 + rq + r;
                int col = n_base + nt * 16 + rl;
                out[(size_t)row * 2048 + col] = (__bf16)acc[mt][nt][r];
            }
}

// ---------------------------------------------------------------------------
// 3-stage pipelined recurrence. 96 wgs x 256. role = blockIdx/32, w = %32.
// wg w (any role) owns h-cols [w*16, w*16+16) x 4 gates.
// Static LDS: 33.0 KB staging + 8.7 KB gates = 41.7 KB.
// ---------------------------------------------------------------------------
__global__ __launch_bounds__(256, 1) void lstm_pipe3(
    const __bf16* __restrict__ xp0,    // [32768][2048] bf16, row = t*32+b
    const __bf16* __restrict__ WB0,    // W_hh0 packed
    const __bf16* __restrict__ WBw1,   // W_hh1 packed
    const __bf16* __restrict__ WBi1,   // W_ih1 packed
    const float* __restrict__ bias0,
    const float* __restrict__ bias1,
    u64* __restrict__ hbuf0,           // [2][8192] {data,phase} pairs, zeroed
    u64* __restrict__ hbuf1,           // [2][8192] pairs, zeroed
    u64* __restrict__ hring,           // [16][8192] hs0 pairs, zeroed
    __bf16* __restrict__ xp1r,         // [4][32][2048] ring
    float* __restrict__ out_f32,       // [32][1024][512]
    float* __restrict__ hn_out,        // [2][32][512]
    float* __restrict__ cn_out,        // [2][32][512]
    int* __restrict__ fX,              // [32][1024] zeroed (XP1 -> L1, + L0 BP)
    int* __restrict__ fL1) {           // [32][1024] zeroed (L1 -> XP1 BP)
    const int tid  = threadIdx.x;
    const int role = blockIdx.x >> 5;   // 0=L0, 1=XP1, 2=L1
    const int w    = blockIdx.x & 31;
    const int lane = tid & 63;
    const int wv   = tid >> 6;

    __shared__ __bf16 lds_h[32 * 516];  // staged snapshot (stride 516)
    __shared__ float  g_lds[32 * 68];   // gates [32 b][64 cols +4]

    // --- weights resident in registers (64 VGPRs/lane) ---
    bf16x8 wreg[16];
    {
        const __bf16* WB = (role == 0) ? WB0 : (role == 1) ? WBi1 : WBw1;
        const __bf16* wb = WB + (size_t)(w * 4 + wv) * 16 * 512 + lane * 8;
#pragma unroll
        for (int kk = 0; kk < 16; kk++) wreg[kk] = *(const bf16x8*)(wb + kk * 512);
    }

    // --- elementwise mapping: thread -> (b, j0, j0+1) ---
    const int b  = tid >> 3;
    const int jp = tid & 7;
    const int j0 = w * 16 + jp * 2;
    const int pi = b * 256 + w * 8 + jp;   // pair index in snapshots
    const int arow = lane & 15;
    const int kq8  = (lane >> 4) * 8;

    f32x2 bsv[4];
    if (role != 1) {
        const float* bias = (role == 0) ? bias0 : bias1;
#pragma unroll
        for (int g = 0; g < 4; g++) bsv[g] = *(const f32x2*)(bias + g * 512 + j0);
    }
    float cc0 = 0.f, cc1 = 0.f;

    if (role == 0) {
        // =================== L0: layer-0 recurrence ===================
        u32 xc[4], xn[4];
#pragma unroll
        for (int g = 0; g < 4; g++)
            xc[g] = *(const u32*)(xp0 + (size_t)b * 2048 + g * 512 + j0);

        for (int t = 0; t < 1024; t++) {
            // ring backpressure pre-load: write-once addr, overlaps the poll
            u32 bp = 1;
            if (tid < 32 && t >= 16)
                bp = (u32)AL32(&fX[tid * 1024 + t - 16]);

            // h0(t) self-validating poll (selective retry)
            u64 hv[16];
            if (t > 0) {
                poll_sel16(hbuf0 + (size_t)(t & 1) * 8192, tid, (u32)(t >> 1) + 1, hv);
            } else {
#pragma unroll
                for (int i = 0; i < 16; i++) hv[i] = 0;
            }
            // backpressure finalize (steady-state: bp already 1)
            if (tid < 32 && t >= 16)
                while (bp == 0) bp = (u32)AL32(&fX[tid * 1024 + t - 16]);

            // xp0 prefetch for t+1 (lands during MFMA, consumed next step)
            {
                int tn = (t < 1023) ? t + 1 : 1023;
#pragma unroll
                for (int g = 0; g < 4; g++)
                    xn[g] = *(const u32*)(xp0 + (size_t)(tn * 32 + b) * 2048 + g * 512 + j0);
            }

            // stage h0 -> lds_h
#pragma unroll
            for (int i = 0; i < 16; i++) {
                int f  = (i * 256 + tid) * 4;
                int br = f >> 9, col = f & 511;
                *(u64*)(lds_h + br * 516 + col) = hv[i];
            }
            __syncthreads();

            // 32 MFMAs: h0(t) @ W_hh0^T
            f32x4 acc0 = (f32x4){0.f, 0.f, 0.f, 0.f};
            f32x4 acc1 = (f32x4){0.f, 0.f, 0.f, 0.f};
#pragma unroll
            for (int kk = 0; kk < 16; kk++) {
                const __bf16* p0 = lds_h + arow * 516 + kq8 + kk * 32;
                const __bf16* p1 = p0 + 16 * 516;
                bf16x8 a0 = frag_from(*(const u64*)p0, *(const u64*)(p0 + 4));
                bf16x8 a1 = frag_from(*(const u64*)p1, *(const u64*)(p1 + 4));
                acc0 = MFMA16(a0, wreg[kk], acc0);
                acc1 = MFMA16(a1, wreg[kk], acc1);
            }
            {
                int col   = wv * 16 + (lane & 15);
                int rbase = (lane >> 4) * 4;
#pragma unroll
                for (int r = 0; r < 4; r++) {
                    g_lds[(rbase + r) * 68 + col]      = acc0[r];
                    g_lds[(16 + rbase + r) * 68 + col] = acc1[r];
                }
            }
            __syncthreads();

            // gates + state update
            float hf0, hf1;
            {
                union { u32 u; __bf16 v2[2]; } xi, xf, xg, xo;
                xi.u = xc[0]; xf.u = xc[1]; xg.u = xc[2]; xo.u = xc[3];
                const float* gl = g_lds + b * 68 + jp * 2;
                f32x2 gi = *(const f32x2*)(gl);
                f32x2 gf = *(const f32x2*)(gl + 16);
                f32x2 gg = *(const f32x2*)(gl + 32);
                f32x2 go = *(const f32x2*)(gl + 48);

                float i0 = fsigm(gi[0] + (float)xi.v2[0] + bsv[0][0]);
                float f0 = fsigm(gf[0] + (float)xf.v2[0] + bsv[1][0]);
                float g0 = ftanh(gg[0] + (float)xg.v2[0] + bsv[2][0]);
                float o0 = fsigm(go[0] + (float)xo.v2[0] + bsv[3][0]);
                cc0 = f0 * cc0 + i0 * g0;
                hf0 = o0 * ftanh(cc0);

                float i1 = fsigm(gi[1] + (float)xi.v2[1] + bsv[0][1]);
                float f1 = fsigm(gf[1] + (float)xf.v2[1] + bsv[1][1]);
                float g1 = ftanh(gg[1] + (float)xg.v2[1] + bsv[2][1]);
                float o1 = fsigm(go[1] + (float)xo.v2[1] + bsv[3][1]);
                cc1 = f1 * cc1 + i1 * g1;
                hf1 = o1 * ftanh(cc1);
            }
            union { __bf16 v2[2]; u32 u; } hu;
            hu.v2[0] = (__bf16)hf0; hu.v2[1] = (__bf16)hf1;

            // fire-and-forget: self pair + hs0 ring pair. No acks, no flags.
            u64 hp_rec = (u64)hu.u | ((u64)((u32)((t + 1) >> 1) + 1) << 32);
            AS64(hbuf0 + (size_t)((t + 1) & 1) * 8192 + pi, hp_rec);
            u64 hp_ring = (u64)hu.u | ((u64)(u32)(t + 1) << 32);
            AS64(hring + (size_t)(t & 15) * 8192 + pi, hp_ring);

            if (t == 1023) {
                *(f32x2*)(hn_out + (size_t)b * 512 + j0) = (f32x2){hf0, hf1};
                *(f32x2*)(cn_out + (size_t)b * 512 + j0) = (f32x2){cc0, cc1};
            }
#pragma unroll
            for (int g = 0; g < 4; g++) xc[g] = xn[g];
        }
    } else if (role == 1) {
        // =================== XP1: xp1(t) = hs0(t) @ W_ih1^T ===================
        u32 bl = 1;   // prefetched fL1[w][t-4]
        for (int t = 0; t < 1024; t++) {
            // xp1r slot t&3 backpressure (4-step slack, prefetched)
            if (tid == 32 && t >= 4)
                while (bl == 0) bl = (u32)AL32(&fL1[w * 1024 + t - 4]);

            // hs0(t) ring pair-poll (fan-in 32, selective retry)
            u64 hvx[16];
            poll_sel16(hring + (size_t)(t & 15) * 8192, tid, (u32)(t + 1), hvx);

            // prefetch next backpressure flag (index (t+1)-4 = t-3)
            if (tid == 32 && t >= 3) bl = (u32)AL32(&fL1[w * 1024 + t - 3]);

            // stage hs0 -> lds_h
#pragma unroll
            for (int i = 0; i < 16; i++) {
                int f  = (i * 256 + tid) * 4;
                int br = f >> 9, col = f & 511;
                *(u64*)(lds_h + br * 516 + col) = hvx[i];
            }
            __syncthreads();

            // 32 MFMAs: hs0(t) @ W_ih1^T
            f32x4 acc0 = (f32x4){0.f, 0.f, 0.f, 0.f};
            f32x4 acc1 = (f32x4){0.f, 0.f, 0.f, 0.f};
#pragma unroll
            for (int kk = 0; kk < 16; kk++) {
                const __bf16* p0 = lds_h + arow * 516 + kq8 + kk * 32;
                const __bf16* p1 = p0 + 16 * 516;
                bf16x8 a0 = frag_from(*(const u64*)p0, *(const u64*)(p0 + 4));
                bf16x8 a1 = frag_from(*(const u64*)p1, *(const u64*)(p1 + 4));
                acc0 = MFMA16(a0, wreg[kk], acc0);
                acc1 = MFMA16(a1, wreg[kk], acc1);
            }
            {
                int col   = wv * 16 + (lane & 15);
                int rbase = (lane >> 4) * 4;
#pragma unroll
                for (int r = 0; r < 4; r++) {
                    g_lds[(rbase + r) * 68 + col]      = acc0[r];
                    g_lds[(16 + rbase + r) * 68 + col] = acc1[r];
                }
            }
            __syncthreads();

            // pack projection to bf16, store to ring, ack, flag (proven edge)
            const float* gl = g_lds + b * 68 + jp * 2;
            __bf16* xd = xp1r + (size_t)(t & 3) * 65536 + (size_t)b * 2048 + j0;
#pragma unroll
            for (int g = 0; g < 4; g++) {
                f32x2 gv = *(const f32x2*)(gl + g * 16);
                union { __bf16 v2[2]; u32 u; } pu;
                pu.v2[0] = (__bf16)gv[0]; pu.v2[1] = (__bf16)gv[1];
                AS32((u32*)(xd + g * 512), pu.u);
            }
            asm volatile("s_waitcnt vmcnt(0)" ::: "memory");
            __syncthreads();
            if (tid == 0) AS32(&fX[w * 1024 + t], 1);
        }
    } else {
        // =================== L1: layer-1 recurrence ===================
        u32 fx = 0;   // prefetched fX[w][t]
        for (int t = 0; t < 1024; t++) {
            // fan-in-1 gate for xp words (prefetched 1 step early -> usually 0-cost)
            if (tid == 32)
                while (fx == 0) fx = (u32)AL32(&fX[w * 1024 + t]);
            asm volatile("" ::: "memory");
            __syncthreads();

            // xp word loads (valid: fX confirmed before this barrier)
            u32 xpr[4];
            {
                const __bf16* xs = xp1r + (size_t)(t & 3) * 65536 + (size_t)b * 2048 + j0;
#pragma unroll
                for (int g = 0; g < 4; g++)
                    xpr[g] = AL32((const u32*)(xs + g * 512));
            }
            // prefetch next fX
            if (tid == 32) fx = (t < 1023) ? (u32)AL32(&fX[w * 1024 + t + 1]) : 1u;

            // h1(t) self-validating poll (selective retry)
            u64 hv[16];
            if (t > 0) {
                poll_sel16(hbuf1 + (size_t)(t & 1) * 8192, tid, (u32)(t >> 1) + 1, hv);
            } else {
#pragma unroll
                for (int i = 0; i < 16; i++) hv[i] = 0;
            }

            // stage h1 -> lds_h
#pragma unroll
            for (int i = 0; i < 16; i++) {
                int f  = (i * 256 + tid) * 4;
                int br = f >> 9, col = f & 511;
                *(u64*)(lds_h + br * 516 + col) = hv[i];
            }
            __syncthreads();

            // 32 MFMAs: h1(t) @ W_hh1^T
            f32x4 acc0 = (f32x4){0.f, 0.f, 0.f, 0.f};
            f32x4 acc1 = (f32x4){0.f, 0.f, 0.f, 0.f};
#pragma unroll
            for (int kk = 0; kk < 16; kk++) {
                const __bf16* p0 = lds_h + arow * 516 + kq8 + kk * 32;
                const __bf16* p1 = p0 + 16 * 516;
                bf16x8 a0 = frag_from(*(const u64*)p0, *(const u64*)(p0 + 4));
                bf16x8 a1 = frag_from(*(const u64*)p1, *(const u64*)(p1 + 4));
                acc0 = MFMA16(a0, wreg[kk], acc0);
                acc1 = MFMA16(a1, wreg[kk], acc1);
            }
            {
                int col   = wv * 16 + (lane & 15);
                int rbase = (lane >> 4) * 4;
#pragma unroll
                for (int r = 0; r < 4; r++) {
                    g_lds[(rbase + r) * 68 + col]      = acc0[r];
                    g_lds[(16 + rbase + r) * 68 + col] = acc1[r];
                }
            }
            __syncthreads();

            // gates + state update
            float hf0, hf1;
            {
                union { u32 u; __bf16 v2[2]; } xi, xf, xg, xo;
                xi.u = xpr[0]; xf.u = xpr[1]; xg.u = xpr[2]; xo.u = xpr[3];
                const float* gl = g_lds + b * 68 + jp * 2;
                f32x2 gi = *(const f32x2*)(gl);
                f32x2 gf = *(const f32x2*)(gl + 16);
                f32x2 gg = *(const f32x2*)(gl + 32);
                f32x2 go = *(const f32x2*)(gl + 48);

                float i0 = fsigm(gi[0] + (float)xi.v2[0] + bsv[0][0]);
                float f0 = fsigm(gf[0] + (float)xf.v2[0] + bsv[1][0]);
                float g0 = ftanh(gg[0] + (float)xg.v2[0] + bsv[2][0]);
                float o0 = fsigm(go[0] + (float)xo.v2[0] + bsv[3][0]);
                cc0 = f0 * cc0 + i0 * g0;
                hf0 = o0 * ftanh(cc0);

                float i1 = fsigm(gi[1] + (float)xi.v2[1] + bsv[0][1]);
                float f1 = fsigm(gf[1] + (float)xf.v2[1] + bsv[1][1]);
                float g1 = ftanh(gg[1] + (float)xg.v2[1] + bsv[2][1]);
                float o1 = fsigm(go[1] + (float)xo.v2[1] + bsv[3][1]);
                cc1 = f1 * cc1 + i1 * g1;
                hf1 = o1 * ftanh(cc1);
            }
            union { __bf16 v2[2]; u32 u; } hu;
            hu.v2[0] = (__bf16)hf0; hu.v2[1] = (__bf16)hf1;

            // fire-and-forget: self pair, output, ring-consumed flag (end of
            // step -> xp loads consumed many 100s of cycles before; XP1 acts
            // on the flag >=2 one-way latencies later).
            u64 hp_rec = (u64)hu.u | ((u64)((u32)((t + 1) >> 1) + 1) << 32);
            AS64(hbuf1 + (size_t)((t + 1) & 1) * 8192 + pi, hp_rec);
            *(f32x2*)(out_f32 + (size_t)b * 524288 + (size_t)t * 512 + j0) =
                (f32x2){hf0, hf1};
            if (t == 1023) {
                *(f32x2*)(hn_out + 16384 + (size_t)b * 512 + j0) = (f32x2){hf0, hf1};
                *(f32x2*)(cn_out + 16384 + (size_t)b * 512 + j0) = (f32x2){cc0, cc1};
            }
            if (tid == 0) AS32(&fL1[w * 1024 + t], 1);
        }
    }
}

// ---------------------------------------------------------------------------
extern "C" void kernel_launch(void* const* d_in, const int* in_sizes, int n_in,
                              void* d_out, int out_size, void* d_ws, size_t ws_size,
                              hipStream_t stream) {
    (void)in_sizes; (void)n_in; (void)out_size; (void)ws_size;
    const float* x    = (const float*)d_in[0];  // [32][1024][256] fp32
    const float* Wih0 = (const float*)d_in[1];  // [2048][256] fp32
    const float* b0   = (const float*)d_in[2];  // [2048] fp32
    const float* Whh0 = (const float*)d_in[3];  // [2048][512] fp32
    const float* Wih1 = (const float*)d_in[4];  // [2048][512] fp32
    const float* b1   = (const float*)d_in[5];  // [2048] fp32
    const float* Whh1 = (const float*)d_in[6];  // [2048][512] fp32
    float* dout = (float*)d_out;  // fp32: out(16777216) | h_n(2*16384) | c_n(2*16384)

    char* wsb = (char*)d_ws;
    int*    fX    = (int*)wsb;                                  // 128 KB
    int*    fL1   = (int*)(wsb + (128 << 10));                  // 128 KB
    u64*    hbuf0 = (u64*)(wsb + (256 << 10));                  // 128 KB
    u64*    hbuf1 = (u64*)(wsb + (384 << 10));                  // 128 KB
    u64*    hring = (u64*)(wsb + (512 << 10));                  // 1 MB
    __bf16* xp1r  = (__bf16*)(wsb + (1536 << 10));              // 512 KB
    __bf16* WB0   = (__bf16*)(wsb + (2 << 20));                 // 2 MB
    __bf16* WBw1  = (__bf16*)(wsb + (4 << 20));                 // 2 MB
    __bf16* WBi1  = (__bf16*)(wsb + (6 << 20));                 // 2 MB
    __bf16* xpb   = (__bf16*)(wsb + (8 << 20));                 // 128 MB

    // zero flags + pair double-buffers + hs0 ring (contiguous 1.5 MB)
    (void)hipMemsetAsync(wsb, 0, 1536 << 10, stream);

    pack_w3<<<dim3(1536), dim3(256), 0, stream>>>(Whh0, Whh1, Wih1, WB0, WBw1, WBi1);

    // xp0 = x @ Wih0^T  (K=256, fp32 A, permuted rows)
    gemm_xp<<<dim3(4096), dim3(256), 0, stream>>>(x, Wih0, xpb, 256);

    lstm_pipe3<<<dim3(96), dim3(256), 0, stream>>>(
        xpb, WB0, WBw1, WBi1, b0, b1, hbuf0, hbuf1, hring, xp1r,
        dout, dout + 16777216, dout + 16777216 + 32768, fX, fL1);
}